// Round 17
// baseline (169.736 us; speedup 1.0000x reference)
//
#include <hip/hip_runtime.h>
#include <math.h>

#define B_   8
#define M_   4096
#define N_   4096
#define DM   1024
#define DC   768
#define DH   16
#define PD   8                // register pipeline depth (power of 2)
#define KVBLOCKS (B_*N_/32)   // 1024
#define QBLOCKS  (B_*M_/32)   // 1024

typedef float v4f __attribute__((ext_vector_type(4)));
typedef __attribute__((ext_vector_type(8))) short short8v;   // 8 bf16 (4 VGPR)
typedef __attribute__((ext_vector_type(4))) float f32x4;
typedef __attribute__((ext_vector_type(4))) int int4v;

__device__ __forceinline__ float elu1(float t) {
    return t > 0.0f ? t + 1.0f : expf(t);
}
__device__ __forceinline__ float4 ld4(const float* p) { return *reinterpret_cast<const float4*>(p); }
__device__ __forceinline__ void  st4(float* p, float4 v) { *reinterpret_cast<float4*>(p) = v; }
__device__ __forceinline__ void  st4nt(float* p, float4 v) {
    v4f w; w.x = v.x; w.y = v.y; w.z = v.z; w.w = v.w;
    __builtin_nontemporal_store(w, reinterpret_cast<v4f*>(p));
}
__device__ __forceinline__ void fma4(float4& a, float s, float4 w) {
    a.x = fmaf(s, w.x, a.x); a.y = fmaf(s, w.y, a.y);
    a.z = fmaf(s, w.z, a.z); a.w = fmaf(s, w.w, a.w);
}
__device__ __forceinline__ short f2bf(float f) {
    unsigned u = __float_as_uint(f);
    unsigned r = 0x7FFFu + ((u >> 16) & 1u);
    return (short)((u + r) >> 16);
}
__device__ __forceinline__ unsigned cvtpk(float a, float b) {
    unsigned r;
    asm("v_cvt_pk_bf16_f32 %0, %1, %2" : "=v"(r) : "v"(a), "v"(b));
    return r;
}
__device__ __forceinline__ short8v mk_frag(const float4& a, const float4& b) {
    int4v iv;
    iv.x = (int)cvtpk(a.x, a.y);
    iv.y = (int)cvtpk(a.z, a.w);
    iv.z = (int)cvtpk(b.x, b.y);
    iv.w = (int)cvtpk(b.z, b.w);
    union { int4v i; short8v s; } u; u.i = iv;
    return u.s;
}

// ---------------------------------------------------------------------------
// prep: build MFMA B-fragments from Wq/Wk/Wv (bf16) + zero per-batch counters.
// For k-step kt, lane l holds W[kt*32 + (l>>4)*8 + j][l&15], j=0..7.
// ---------------------------------------------------------------------------
__global__ __launch_bounds__(256) void prep(
    const float* __restrict__ Wq, const float* __restrict__ Wk,
    const float* __restrict__ Wv,
    short* __restrict__ fq, short* __restrict__ fk, short* __restrict__ fv,
    unsigned* __restrict__ cnt)
{
    if (blockIdx.x == 0 && threadIdx.x < B_) cnt[threadIdx.x] = 0;
    const int id = blockIdx.x * 256 + threadIdx.x;
    if (id >= 80 * 64) return;
    const int l  = id & 63;
    const int kt = id >> 6;
    const float* W; short* dst; int ktl;
    if (kt < 32)      { W = Wq; dst = fq; ktl = kt; }
    else if (kt < 56) { W = Wk; dst = fk; ktl = kt - 32; }
    else              { W = Wv; dst = fv; ktl = kt - 56; }
    const int k0 = ktl * 32 + (l >> 4) * 8;
    const int d  = l & 15;
    short* o = dst + ((size_t)ktl * 64 + l) * 8;
    #pragma unroll
    for (int j = 0; j < 8; ++j)
        o[j] = f2bf(W[(size_t)(k0 + j) * DH + d]);
}

// ---------------------------------------------------------------------------
// kvr: 32 rows/block, wave = {row-tile rt=w&1, k-half kh=w>>1}; MFMA K/V,
// combine k-halves in LDS, partial KtV(16x16)+Ksum -> own part slice; the
// last block per batch (atomic counter) reduces 128 slices -> comb[b][272].
// grid = B_*N_/32 = 1024.
// ---------------------------------------------------------------------------
__global__ __launch_bounds__(256) void kvr(
    const float* __restrict__ ctx,
    const short* __restrict__ fk, const short* __restrict__ fv,
    const float* __restrict__ bk, const float* __restrict__ bv,
    float* __restrict__ part, float* __restrict__ comb,
    unsigned* __restrict__ cnt)
{
    __shared__ struct {
        float ka[2][2][16][17];
        float va[2][2][16][17];
        float sk[32][17];
        float sv[32][17];
    } sh;
    __shared__ int is_last;

    const int t  = threadIdx.x;
    const int l  = t & 63;
    const int w  = t >> 6;
    const int rt = w & 1;
    const int kh = w >> 1;
    const int g4 = l >> 4;
    const int lr = l & 15;

    float4 pa[PD], pb[PD];
    const size_t row0 = (size_t)blockIdx.x * 32;
    const float* src = ctx + (row0 + rt*16 + lr) * DC + kh*384 + g4*8;
    f32x4 accK = {0,0,0,0}, accV = {0,0,0,0};

    #pragma unroll
    for (int i = 0; i < PD; ++i) {
        pa[i] = ld4(src + i*32);
        pb[i] = ld4(src + i*32 + 4);
    }
    #pragma unroll
    for (int kt = 0; kt < 12; ++kt) {
        const int st = kt & (PD-1);
        const short8v a = mk_frag(pa[st], pb[st]);
        if (kt + PD < 12) {
            pa[st] = ld4(src + (kt+PD)*32);
            pb[st] = ld4(src + (kt+PD)*32 + 4);
        }
        const int ktg = kh*12 + kt;
        const short8v bkf = *reinterpret_cast<const short8v*>(fk + ((size_t)ktg*64 + l)*8);
        const short8v bvf = *reinterpret_cast<const short8v*>(fv + ((size_t)ktg*64 + l)*8);
        accK = __builtin_amdgcn_mfma_f32_16x16x32_bf16(a, bkf, accK, 0, 0, 0);
        accV = __builtin_amdgcn_mfma_f32_16x16x32_bf16(a, bvf, accV, 0, 0, 0);
    }

    #pragma unroll
    for (int j = 0; j < 4; ++j) {
        sh.ka[rt][kh][g4*4 + j][lr] = accK[j];
        sh.va[rt][kh][g4*4 + j][lr] = accV[j];
    }
    __syncthreads();

    #pragma unroll
    for (int i = t; i < 512; i += 256) {
        const int r = i >> 4, c = i & 15;
        const int rr = r >> 4, wr = r & 15;
        const float kk = sh.ka[rr][0][wr][c] + sh.ka[rr][1][wr][c] + bk[c];
        const float vv = sh.va[rr][0][wr][c] + sh.va[rr][1][wr][c] + bv[c];
        sh.sk[r][c] = elu1(kk);
        sh.sv[r][c] = vv;
    }
    __syncthreads();

    const int d = t >> 4, e = t & 15;
    float acc = 0.f;
    #pragma unroll 16
    for (int n = 0; n < 32; ++n) acc += sh.sk[n][d] * sh.sv[n][e];
    float* p = part + (size_t)blockIdx.x * 272;
    p[t] = acc;
    if (t < DH) {
        float ss = 0.f;
        #pragma unroll 16
        for (int n = 0; n < 32; ++n) ss += sh.sk[n][t];
        p[256 + t] = ss;
    }

    // ---- last-block-per-batch reduction (deterministic fixed-order sum) ----
    const int b = blockIdx.x >> 7;        // 128 blocks per batch
    __threadfence();                      // device-scope release of part slice
    if (t == 0) {
        const unsigned old = atomicAdd(&cnt[b], 1u);
        is_last = (old == 127u);
    }
    __syncthreads();
    if (is_last) {
        for (int idx = t; idx < 272; idx += 256) {
            float s = 0.f;
            #pragma unroll 8
            for (int ch = 0; ch < 128; ++ch)
                s += part[((size_t)b*128 + ch) * 272 + idx];
            comb[(size_t)b*272 + idx] = s;
        }
    }
}

// ---------------------------------------------------------------------------
// qproj: 32 rows/block, grid = B_*M_/32 = 1024.
// Q = elu1(x@Wq+bq) via MFMA (wave = {row-tile, k-half}), o-step, projection.
// Wo per block read once, nt coalesced stores. (r16-proven path)
// ---------------------------------------------------------------------------
__global__ __launch_bounds__(256) void qproj(
    const float* __restrict__ x,
    const short* __restrict__ fq, const float* __restrict__ bq,
    const float* __restrict__ comb,
    const float* __restrict__ Wo, const float* __restrict__ bo,
    float* __restrict__ out)
{
    __shared__ float qa[2][2][16][17];
    __shared__ float ql[32 * DH];
    __shared__ float ol[32 * DH];
    __shared__ float kts[272];

    const int t  = threadIdx.x;
    const int l  = t & 63;
    const int w  = t >> 6;
    const int rt = w & 1;         // row tile: rows [rt*16, rt*16+16)
    const int kh = w >> 1;        // k half: cols [kh*512, kh*512+512)
    const int g4 = l >> 4;
    const int lr = l & 15;
    const size_t row0 = (size_t)blockIdx.x * 32;
    const int b = blockIdx.x >> 7;      // 128 blocks per batch

    // ---- phase 1: Q k-half partial via MFMA (PD-deep pipeline)
    const float* src = x + (row0 + rt*16 + lr) * DM + kh*512 + g4*8;
    float4 pa[PD], pb[PD];
    #pragma unroll
    for (int i = 0; i < PD; ++i) {
        pa[i] = ld4(src + i*32);
        pb[i] = ld4(src + i*32 + 4);
    }
    if (t < 68) st4(&kts[t*4], ld4(comb + (size_t)b*272 + t*4));

    f32x4 accQ = {0,0,0,0};
    #pragma unroll
    for (int kt = 0; kt < 16; ++kt) {
        const int st = kt & (PD-1);
        const short8v a = mk_frag(pa[st], pb[st]);
        if (kt + PD < 16) {
            pa[st] = ld4(src + (kt+PD)*32);
            pb[st] = ld4(src + (kt+PD)*32 + 4);
        }
        const int ktg = kh*16 + kt;
        const short8v bqf = *reinterpret_cast<const short8v*>(fq + ((size_t)ktg*64 + l)*8);
        accQ = __builtin_amdgcn_mfma_f32_16x16x32_bf16(a, bqf, accQ, 0, 0, 0);
    }
    #pragma unroll
    for (int j = 0; j < 4; ++j)
        qa[rt][kh][g4*4 + j][lr] = accQ[j];
    __syncthreads();

    // ---- phase 2: combine k-halves + bias + elu (2 elems/thread)
    #pragma unroll
    for (int i = t; i < 512; i += 256) {
        const int r = i >> 4, c = i & 15;
        const int rr = r >> 4, wr = r & 15;
        const float v = qa[rr][0][wr][c] + qa[rr][1][wr][c] + bq[c];
        ql[r*DH + c] = elu1(v);
    }
    __syncthreads();

    // ---- phase 3: o for 32 rows (threads 0..127)
    if (t < 128) {
        const float* qrow = &ql[(t >> 2) * DH];
        const int jj = (t & 3) * 4;
        float den = 1e-6f;
        float4 num = make_float4(0,0,0,0);
        #pragma unroll
        for (int d4 = 0; d4 < 4; ++d4) {
            const float4 q4  = ld4(&qrow[d4*4]);
            const float4 ks4 = ld4(&kts[256 + d4*4]);
            den += q4.x*ks4.x + q4.y*ks4.y + q4.z*ks4.z + q4.w*ks4.w;
            fma4(num, q4.x, ld4(&kts[(d4*4+0)*DH + jj]));
            fma4(num, q4.y, ld4(&kts[(d4*4+1)*DH + jj]));
            fma4(num, q4.z, ld4(&kts[(d4*4+2)*DH + jj]));
            fma4(num, q4.w, ld4(&kts[(d4*4+3)*DH + jj]));
        }
        const float inv = 1.0f / den;
        float4 o4; o4.x = num.x*inv; o4.y = num.y*inv; o4.z = num.z*inv; o4.w = num.w*inv;
        st4(&ol[(t >> 2)*DH + jj], o4);
    }
    __syncthreads();

    // ---- phase 4: projection, Wo in regs (read once per block), nt stores
    float4 wreg[16];
    #pragma unroll
    for (int e = 0; e < 16; ++e) wreg[e] = ld4(Wo + (size_t)e*DM + t*4);
    const float4 bov = ld4(bo + t*4);

    #pragma unroll 4
    for (int r = 0; r < 32; ++r) {
        float4 a = bov;
        #pragma unroll
        for (int eo = 0; eo < 4; ++eo) {
            const float4 o4 = ld4(&ol[r*DH + eo*4]);
            fma4(a, o4.x, wreg[eo*4+0]); fma4(a, o4.y, wreg[eo*4+1]);
            fma4(a, o4.z, wreg[eo*4+2]); fma4(a, o4.w, wreg[eo*4+3]);
        }
        st4nt(out + (row0 + r)*DM + t*4, a);
    }
}

// ---------------------------------------------------------------------------
extern "C" void kernel_launch(void* const* d_in, const int* in_sizes, int n_in,
                              void* d_out, int out_size, void* d_ws, size_t ws_size,
                              hipStream_t stream) {
    const float* x    = (const float*)d_in[0];
    const float* ctx  = (const float*)d_in[1];
    const float* Wq   = (const float*)d_in[2];
    const float* bq   = (const float*)d_in[3];
    const float* Wk   = (const float*)d_in[4];
    const float* bk   = (const float*)d_in[5];
    const float* Wv   = (const float*)d_in[6];
    const float* bv   = (const float*)d_in[7];
    const float* Wo   = (const float*)d_in[8];
    const float* bo   = (const float*)d_in[9];
    float* out = (float*)d_out;

    float* ws = (float*)d_ws;
    float* comb = ws;                                   // 8*272 f
    float* part = comb + (size_t)B_*272;                // 1024*272 f
    unsigned* cnt = (unsigned*)(part + (size_t)KVBLOCKS*272);  // 8 u32
    short* fq = (short*)(cnt + 64);                     // 32*64*8 bf16
    short* fk = fq + (size_t)32*64*8;                   // 24*64*8
    short* fv = fk + (size_t)24*64*8;                   // 24*64*8

    prep<<<dim3(20), dim3(256), 0, stream>>>(Wq, Wk, Wv, fq, fk, fv, cnt);
    kvr<<<dim3(KVBLOCKS), dim3(256), 0, stream>>>(ctx, fk, fv, bk, bv, part, comb, cnt);
    qproj<<<dim3(QBLOCKS), dim3(256), 0, stream>>>(x, fq, bq, comb, Wo, bo, out);
}

// Round 18
// 72.339 us; speedup vs baseline: 2.3464x; 2.3464x over previous
//
#include <hip/hip_runtime.h>
#include <math.h>

#define B_   8
#define M_   4096
#define N_   4096
#define DM   1024
#define DC   768
#define DH   16
#define PD   8                // register pipeline depth (power of 2)
#define KVBLOCKS (B_*N_/32)   // 1024
#define QBLOCKS  (B_*M_/32)   // 1024
#define CHUNKS   128          // 32-row chunks per batch

typedef float v4f __attribute__((ext_vector_type(4)));
typedef __attribute__((ext_vector_type(8))) short short8v;   // 8 bf16 (4 VGPR)
typedef __attribute__((ext_vector_type(4))) float f32x4;
typedef __attribute__((ext_vector_type(4))) int int4v;

__device__ __forceinline__ float elu1(float t) {
    return t > 0.0f ? t + 1.0f : expf(t);
}
__device__ __forceinline__ float4 ld4(const float* p) { return *reinterpret_cast<const float4*>(p); }
__device__ __forceinline__ void  st4(float* p, float4 v) { *reinterpret_cast<float4*>(p) = v; }
__device__ __forceinline__ void  st4nt(float* p, float4 v) {
    v4f w; w.x = v.x; w.y = v.y; w.z = v.z; w.w = v.w;
    __builtin_nontemporal_store(w, reinterpret_cast<v4f*>(p));
}
__device__ __forceinline__ void fma4(float4& a, float s, float4 w) {
    a.x = fmaf(s, w.x, a.x); a.y = fmaf(s, w.y, a.y);
    a.z = fmaf(s, w.z, a.z); a.w = fmaf(s, w.w, a.w);
}
__device__ __forceinline__ short f2bf(float f) {
    unsigned u = __float_as_uint(f);
    unsigned r = 0x7FFFu + ((u >> 16) & 1u);
    return (short)((u + r) >> 16);
}
__device__ __forceinline__ unsigned cvtpk(float a, float b) {
    unsigned r;
    asm("v_cvt_pk_bf16_f32 %0, %1, %2" : "=v"(r) : "v"(a), "v"(b));
    return r;
}
__device__ __forceinline__ short8v mk_frag(const float4& a, const float4& b) {
    int4v iv;
    iv.x = (int)cvtpk(a.x, a.y);
    iv.y = (int)cvtpk(a.z, a.w);
    iv.z = (int)cvtpk(b.x, b.y);
    iv.w = (int)cvtpk(b.z, b.w);
    union { int4v i; short8v s; } u; u.i = iv;
    return u.s;
}

// ---------------------------------------------------------------------------
// prep: build MFMA B-fragments from Wq/Wk/Wv (bf16).
// For k-step kt, lane l holds W[kt*32 + (l>>4)*8 + j][l&15], j=0..7.
// ---------------------------------------------------------------------------
__global__ __launch_bounds__(256) void prep(
    const float* __restrict__ Wq, const float* __restrict__ Wk,
    const float* __restrict__ Wv,
    short* __restrict__ fq, short* __restrict__ fk, short* __restrict__ fv)
{
    const int id = blockIdx.x * 256 + threadIdx.x;
    if (id >= 80 * 64) return;
    const int l  = id & 63;
    const int kt = id >> 6;
    const float* W; short* dst; int ktl;
    if (kt < 32)      { W = Wq; dst = fq; ktl = kt; }
    else if (kt < 56) { W = Wk; dst = fk; ktl = kt - 32; }
    else              { W = Wv; dst = fv; ktl = kt - 56; }
    const int k0 = ktl * 32 + (l >> 4) * 8;
    const int d  = l & 15;
    short* o = dst + ((size_t)ktl * 64 + l) * 8;
    #pragma unroll
    for (int j = 0; j < 8; ++j)
        o[j] = f2bf(W[(size_t)(k0 + j) * DH + d]);
}

// ---------------------------------------------------------------------------
// kvr: 32 rows/block, wave = {row-tile rt=w&1, k-half kh=w>>1}; MFMA K/V,
// combine k-halves in LDS, partial KtV(16x16)+Ksum -> part slice (plain
// stores, no atomics/fences). grid = B_*N_/32 = 1024. (r15-proven)
// ---------------------------------------------------------------------------
__global__ __launch_bounds__(256) void kvr(
    const float* __restrict__ ctx,
    const short* __restrict__ fk, const short* __restrict__ fv,
    const float* __restrict__ bk, const float* __restrict__ bv,
    float* __restrict__ part)
{
    __shared__ struct {
        float ka[2][2][16][17];
        float va[2][2][16][17];
        float sk[32][17];
        float sv[32][17];
    } sh;

    const int t  = threadIdx.x;
    const int l  = t & 63;
    const int w  = t >> 6;
    const int rt = w & 1;
    const int kh = w >> 1;
    const int g4 = l >> 4;
    const int lr = l & 15;

    float4 pa[PD], pb[PD];
    const size_t row0 = (size_t)blockIdx.x * 32;
    const float* src = ctx + (row0 + rt*16 + lr) * DC + kh*384 + g4*8;
    f32x4 accK = {0,0,0,0}, accV = {0,0,0,0};

    #pragma unroll
    for (int i = 0; i < PD; ++i) {
        pa[i] = ld4(src + i*32);
        pb[i] = ld4(src + i*32 + 4);
    }
    #pragma unroll
    for (int kt = 0; kt < 12; ++kt) {
        const int st = kt & (PD-1);
        const short8v a = mk_frag(pa[st], pb[st]);
        if (kt + PD < 12) {
            pa[st] = ld4(src + (kt+PD)*32);
            pb[st] = ld4(src + (kt+PD)*32 + 4);
        }
        const int ktg = kh*12 + kt;
        const short8v bkf = *reinterpret_cast<const short8v*>(fk + ((size_t)ktg*64 + l)*8);
        const short8v bvf = *reinterpret_cast<const short8v*>(fv + ((size_t)ktg*64 + l)*8);
        accK = __builtin_amdgcn_mfma_f32_16x16x32_bf16(a, bkf, accK, 0, 0, 0);
        accV = __builtin_amdgcn_mfma_f32_16x16x32_bf16(a, bvf, accV, 0, 0, 0);
    }

    #pragma unroll
    for (int j = 0; j < 4; ++j) {
        sh.ka[rt][kh][g4*4 + j][lr] = accK[j];
        sh.va[rt][kh][g4*4 + j][lr] = accV[j];
    }
    __syncthreads();

    #pragma unroll
    for (int i = t; i < 512; i += 256) {
        const int r = i >> 4, c = i & 15;
        const int rr = r >> 4, wr = r & 15;
        const float kk = sh.ka[rr][0][wr][c] + sh.ka[rr][1][wr][c] + bk[c];
        const float vv = sh.va[rr][0][wr][c] + sh.va[rr][1][wr][c] + bv[c];
        sh.sk[r][c] = elu1(kk);
        sh.sv[r][c] = vv;
    }
    __syncthreads();

    const int d = t >> 4, e = t & 15;
    float acc = 0.f;
    #pragma unroll 16
    for (int n = 0; n < 32; ++n) acc += sh.sk[n][d] * sh.sv[n][e];
    float* p = part + (size_t)blockIdx.x * 272;
    p[t] = acc;
    if (t < DH) {
        float ss = 0.f;
        #pragma unroll 16
        for (int n = 0; n < 32; ++n) ss += sh.sk[n][t];
        p[256 + t] = ss;
    }
}

// ---------------------------------------------------------------------------
// reduce2: combine 128 partials/batch -> comb[b][272]
// ---------------------------------------------------------------------------
__global__ __launch_bounds__(320) void reduce2(
    const float* __restrict__ part, float* __restrict__ comb)
{
    const int b = blockIdx.x;
    const int t = threadIdx.x;
    if (t < 272) {
        float s = 0.f;
        #pragma unroll
        for (int ch = 0; ch < CHUNKS; ++ch)
            s += part[((size_t)b*CHUNKS + ch) * 272 + t];
        comb[(size_t)b*272 + t] = s;
    }
}

// ---------------------------------------------------------------------------
// qproj: 32 rows/block, grid = B_*M_/32 = 1024.
// Q = elu1(x@Wq+bq) via MFMA (wave = {row-tile, k-half}), o-step, projection.
// Wo per block read once, nt coalesced stores. (r16-proven path)
// ---------------------------------------------------------------------------
__global__ __launch_bounds__(256) void qproj(
    const float* __restrict__ x,
    const short* __restrict__ fq, const float* __restrict__ bq,
    const float* __restrict__ comb,
    const float* __restrict__ Wo, const float* __restrict__ bo,
    float* __restrict__ out)
{
    __shared__ float qa[2][2][16][17];
    __shared__ float ql[32 * DH];
    __shared__ float ol[32 * DH];
    __shared__ float kts[272];

    const int t  = threadIdx.x;
    const int l  = t & 63;
    const int w  = t >> 6;
    const int rt = w & 1;         // row tile: rows [rt*16, rt*16+16)
    const int kh = w >> 1;        // k half: cols [kh*512, kh*512+512)
    const int g4 = l >> 4;
    const int lr = l & 15;
    const size_t row0 = (size_t)blockIdx.x * 32;
    const int b = blockIdx.x >> 7;      // 128 blocks per batch

    // ---- phase 1: Q k-half partial via MFMA (PD-deep pipeline)
    const float* src = x + (row0 + rt*16 + lr) * DM + kh*512 + g4*8;
    float4 pa[PD], pb[PD];
    #pragma unroll
    for (int i = 0; i < PD; ++i) {
        pa[i] = ld4(src + i*32);
        pb[i] = ld4(src + i*32 + 4);
    }
    if (t < 68) st4(&kts[t*4], ld4(comb + (size_t)b*272 + t*4));

    f32x4 accQ = {0,0,0,0};
    #pragma unroll
    for (int kt = 0; kt < 16; ++kt) {
        const int st = kt & (PD-1);
        const short8v a = mk_frag(pa[st], pb[st]);
        if (kt + PD < 16) {
            pa[st] = ld4(src + (kt+PD)*32);
            pb[st] = ld4(src + (kt+PD)*32 + 4);
        }
        const int ktg = kh*16 + kt;
        const short8v bqf = *reinterpret_cast<const short8v*>(fq + ((size_t)ktg*64 + l)*8);
        accQ = __builtin_amdgcn_mfma_f32_16x16x32_bf16(a, bqf, accQ, 0, 0, 0);
    }
    #pragma unroll
    for (int j = 0; j < 4; ++j)
        qa[rt][kh][g4*4 + j][lr] = accQ[j];
    __syncthreads();

    // ---- phase 2: combine k-halves + bias + elu (2 elems/thread)
    #pragma unroll
    for (int i = t; i < 512; i += 256) {
        const int r = i >> 4, c = i & 15;
        const int rr = r >> 4, wr = r & 15;
        const float v = qa[rr][0][wr][c] + qa[rr][1][wr][c] + bq[c];
        ql[r*DH + c] = elu1(v);
    }
    __syncthreads();

    // ---- phase 3: o for 32 rows (threads 0..127)
    if (t < 128) {
        const float* qrow = &ql[(t >> 2) * DH];
        const int jj = (t & 3) * 4;
        float den = 1e-6f;
        float4 num = make_float4(0,0,0,0);
        #pragma unroll
        for (int d4 = 0; d4 < 4; ++d4) {
            const float4 q4  = ld4(&qrow[d4*4]);
            const float4 ks4 = ld4(&kts[256 + d4*4]);
            den += q4.x*ks4.x + q4.y*ks4.y + q4.z*ks4.z + q4.w*ks4.w;
            fma4(num, q4.x, ld4(&kts[(d4*4+0)*DH + jj]));
            fma4(num, q4.y, ld4(&kts[(d4*4+1)*DH + jj]));
            fma4(num, q4.z, ld4(&kts[(d4*4+2)*DH + jj]));
            fma4(num, q4.w, ld4(&kts[(d4*4+3)*DH + jj]));
        }
        const float inv = 1.0f / den;
        float4 o4; o4.x = num.x*inv; o4.y = num.y*inv; o4.z = num.z*inv; o4.w = num.w*inv;
        st4(&ol[(t >> 2)*DH + jj], o4);
    }
    __syncthreads();

    // ---- phase 4: projection, Wo in regs (read once per block), nt stores
    float4 wreg[16];
    #pragma unroll
    for (int e = 0; e < 16; ++e) wreg[e] = ld4(Wo + (size_t)e*DM + t*4);
    const float4 bov = ld4(bo + t*4);

    #pragma unroll 4
    for (int r = 0; r < 32; ++r) {
        float4 a = bov;
        #pragma unroll
        for (int eo = 0; eo < 4; ++eo) {
            const float4 o4 = ld4(&ol[r*DH + eo*4]);
            fma4(a, o4.x, wreg[eo*4+0]); fma4(a, o4.y, wreg[eo*4+1]);
            fma4(a, o4.z, wreg[eo*4+2]); fma4(a, o4.w, wreg[eo*4+3]);
        }
        st4nt(out + (row0 + r)*DM + t*4, a);
    }
}

// ---------------------------------------------------------------------------
extern "C" void kernel_launch(void* const* d_in, const int* in_sizes, int n_in,
                              void* d_out, int out_size, void* d_ws, size_t ws_size,
                              hipStream_t stream) {
    const float* x    = (const float*)d_in[0];
    const float* ctx  = (const float*)d_in[1];
    const float* Wq   = (const float*)d_in[2];
    const float* bq   = (const float*)d_in[3];
    const float* Wk   = (const float*)d_in[4];
    const float* bk   = (const float*)d_in[5];
    const float* Wv   = (const float*)d_in[6];
    const float* bv   = (const float*)d_in[7];
    const float* Wo   = (const float*)d_in[8];
    const float* bo   = (const float*)d_in[9];
    float* out = (float*)d_out;

    float* ws = (float*)d_ws;
    float* part = ws;                                   // 1024*272 f
    float* comb = part + (size_t)KVBLOCKS*272;          // 8*272 f
    short* fq = (short*)(comb + (size_t)B_*272);        // 32*64*8 bf16
    short* fk = fq + (size_t)32*64*8;                   // 24*64*8
    short* fv = fk + (size_t)24*64*8;                   // 24*64*8

    prep<<<dim3(20), dim3(256), 0, stream>>>(Wq, Wk, Wv, fq, fk, fv);
    kvr<<<dim3(KVBLOCKS), dim3(256), 0, stream>>>(ctx, fk, fv, bk, bv, part);
    reduce2<<<dim3(B_), dim3(320), 0, stream>>>(part, comb);
    qproj<<<dim3(QBLOCKS), dim3(256), 0, stream>>>(x, fq, bq, comb, Wo, bo, out);
}